// Round 9
// baseline (34.899 us; speedup 1.0000x reference)
//
#include <hip/hip_runtime.h>

typedef unsigned short u16;
typedef unsigned int u32;
typedef __attribute__((ext_vector_type(2))) unsigned int u32x2;
typedef __attribute__((ext_vector_type(8))) short bf16x8;
typedef __attribute__((ext_vector_type(4))) float f32x4;

#define CIN 128
#define OC 128
#define NP 1024        // 32*32 spatial
#define KTOT 1152      // 9*128, k = rs*128 + c
#define NSTEP 18
#define BK 64
#define TILE_U16 8192  // 16 KB A-tile per (sample, step)
#define SAMP_U16 (NSTEP * TILE_U16)

typedef const u32 __attribute__((address_space(1)))* gptr_t;
typedef u32 __attribute__((address_space(3)))* lptr_t;

__device__ __forceinline__ u16 f2bf(float f) {
  unsigned b = __builtin_bit_cast(unsigned, f);
  b += 0x7fffu + ((b >> 16) & 1u);   // RNE; inputs are finite
  return (u16)(b >> 16);
}

// w[i][oc][c][r][s] f32 -> wbf2: per (i,step) a flat 16KB tile, PRE-SWIZZLED:
//   tile[(row*8 + (slotk ^ (row&7)))*8 + e] = w_bf16[k = step*64 + slotk*8 + e]
// so conv's linear global_load_lds reproduces the proven Asw layout exactly.
__global__ void wcvt_kernel(const float* __restrict__ w, u16* __restrict__ wbf2) {
  __shared__ u16 lds[KTOT];
  const int blk = blockIdx.x;        // i*128 + row(oc)
  const int t = threadIdx.x;         // 0..127
  const int i = blk >> 7, row = blk & 127;
  const float* src = w + (size_t)blk * KTOT;
#pragma unroll
  for (int e = 0; e < 9; ++e) {
    int idx = t + 128 * e;           // coalesced read
    lds[idx] = f2bf(src[idx]);       // lds[c*9+rs] (input order)
  }
  __syncthreads();
  u16* dst = wbf2 + (size_t)i * SAMP_U16;
  const int rsw = row & 7;
#pragma unroll
  for (int e = 0; e < 9; ++e) {
    const int o = t + 128 * e;       // k = rs*128 + c ; rs=e, c=t
    const int s = o >> 6;            // k-step
    const int slotk = (o >> 3) & 7;
    const int ee = o & 7;
    dst[s * TILE_U16 + (row * 8 + (slotk ^ rsw)) * 8 + ee] = lds[t * 9 + e];
  }
}

// Xs: 4 rows x 34 cols x 128 ch bf16, 16B slots, XOR swizzle
//   slot' = cslot ^ (col&7); u16 idx = ((r*34+col)*16 + slot')*8 + (c&7)
// Asw: double-buffered flat 16KB tiles filled by global_load_lds (linear).
// LDS = 34,816 + 32,768 = 67,584 B -> 2 blocks/CU (135 KB of 160 KB).
__global__ __launch_bounds__(128, 1) void conv_mfma(
    const float* __restrict__ x,     // [32][128][32][32] f32
    const u16* __restrict__ wbf2,    // pre-swizzled A-tiles
    const float* __restrict__ bias,  // [32][1][128]
    float* __restrict__ out) {       // [32][1][128][32][32]
  __shared__ u16 Xs[4 * 34 * 128];
  __shared__ u16 Asw[2][OC * BK];

  // grid 512 = 8 XCDs x 64; bijective XCD swizzle -> 4 samples per XCD
  const int wg = (int)blockIdx.x;
  const int swz = (wg & 7) * 64 + (wg >> 3);
  const int i  = swz >> 4;
  const int pt = swz & 15;
  const int p0 = pt * 64;            // 64 px = image rows {2pt, 2pt+1}
  const int tid = (int)threadIdx.x;  // 0..127, 2 waves
  const int lane = tid & 63;
  const int wm = tid >> 6;           // oc half (wave id)
  const int lcol = lane & 15;
  const int lhi  = lane >> 4;        // k-subslot 0..3

  const float* xi = x + (size_t)i * CIN * NP;
  const u16*   wt = wbf2 + (size_t)i * SAMP_U16;

  // async A-stage: 8 x 1KB wave-chunks; LDS dest wave-uniform, global per-lane
#define STAGE(step, buf) do {                                          \
    const char* _tb = (const char*)(wt + (step) * TILE_U16);           \
    _Pragma("unroll")                                                  \
    for (int _j = 0; _j < 8; ++_j) {                                   \
      const int _off = wm * 8192 + _j * 1024;                          \
      __builtin_amdgcn_global_load_lds(                                \
          (gptr_t)(_tb + _off + lane * 16),                            \
          (lptr_t)((char*)&Asw[buf][0] + _off), 16, 0, 0);             \
    }                                                                  \
  } while (0)

  STAGE(0, 0);                       // in flight during x-stage

  // ---------- one-time x-stage: rows yr = 2pt-1 .. 2pt+2 ----------
  {
    const int xx = tid & 31;         // image col -> LDS col xx+1
    const int cg = tid >> 5;         // channel group 0..3 (32 ch each)
    const int col = xx + 1;
    const int csw = col & 7;
#pragma unroll
    for (int r = 0; r < 4; ++r) {
      const int yr = 2 * pt - 1 + r;
      float v[32];
      if ((unsigned)yr < 32u) {
        const float* src = xi + (size_t)(cg * 32) * NP + yr * 32 + xx;
#pragma unroll
        for (int j = 0; j < 32; ++j) v[j] = src[(size_t)j * NP];
      } else {
#pragma unroll
        for (int j = 0; j < 32; ++j) v[j] = 0.f;
      }
      u32 pk[16];
#pragma unroll
      for (int m = 0; m < 16; ++m)
        pk[m] = (u32)f2bf(v[2 * m]) | ((u32)f2bf(v[2 * m + 1]) << 16);
#pragma unroll
      for (int q = 0; q < 8; ++q) {
        const int cslot = cg * 4 + (q >> 1);
        const int idx = ((r * 34 + col) * 16 + (cslot ^ csw)) * 8 + (q & 1) * 4;
        *(u32x2*)(&Xs[idx]) = (u32x2){pk[2 * q], pk[2 * q + 1]};
      }
    }
    // column halo (col 0 and 33): zeros; 4r x 2c x 16slots = 128 writes
    {
      const int r = tid >> 5;
      const int hc = ((tid >> 4) & 1) ? 33 : 0;
      const int s = tid & 15;
      const int idx = ((r * 34 + hc) * 16 + (s ^ (hc & 7))) * 8;
      *(bf16x8*)(&Xs[idx]) = (bf16x8){0, 0, 0, 0, 0, 0, 0, 0};
    }
  }

  f32x4 acc[4][4];
#pragma unroll
  for (int mi = 0; mi < 4; ++mi)
#pragma unroll
    for (int ni = 0; ni < 4; ++ni)
      acc[mi][ni] = (f32x4){0.f, 0.f, 0.f, 0.f};

  __syncthreads();                   // Xs + Asw[0] ready

#pragma unroll
  for (int step = 0; step < NSTEP; ++step) {
    const int buf = step & 1;
    const int rs = step >> 1;
    const int r3 = rs / 3;
    const int dy = r3 - 1;
    const int dx = (rs - r3 * 3) - 1;
    const int c0s = (step & 1) * 8;  // channel-slot base (64ch/8)

    // issue next tile's async loads; latency hides under the MFMA phase
    if (step + 1 < NSTEP) STAGE(step + 1, buf ^ 1);

    // ---- math: 32 MFMAs per wave per K-step ----
    __builtin_amdgcn_s_setprio(1);
#pragma unroll
    for (int kkk = 0; kkk < 2; ++kkk) {
      bf16x8 af[4], bfr[4];
#pragma unroll
      for (int mi = 0; mi < 4; ++mi) {
        const int row = wm * 64 + mi * 16 + lcol;
        const int slot = (kkk * 4 + lhi) ^ (row & 7);
        af[mi] = *(const bf16x8*)(&Asw[buf][row * BK + slot * 8]);
      }
#pragma unroll
      for (int ni = 0; ni < 4; ++ni) {
        const int srow = 1 + (ni >> 1) + dy;          // always in [0,3]
        const int col  = (ni & 1) * 16 + lcol + 1 + dx;
        const int cslot = c0s + kkk * 4 + lhi;
        const int idx = ((srow * 34 + col) * 16 + (cslot ^ (col & 7))) * 8;
        bfr[ni] = *(const bf16x8*)(&Xs[idx]);
      }
#pragma unroll
      for (int mi = 0; mi < 4; ++mi)
#pragma unroll
        for (int ni = 0; ni < 4; ++ni)
          acc[mi][ni] = __builtin_amdgcn_mfma_f32_16x16x32_bf16(
              af[mi], bfr[ni], acc[mi][ni], 0, 0, 0);
    }
    __builtin_amdgcn_s_setprio(0);

    // one barrier/step: drains the staged loads (vmcnt) + guards WAR on buf^1
    __syncthreads();
  }

  // ---- epilogue (proven): C/D col=lane&15, row=(lane>>4)*4+j ----
  const int row0 = lhi * 4;
#pragma unroll
  for (int mi = 0; mi < 4; ++mi) {
    const int oc = wm * 64 + mi * 16 + row0;
#pragma unroll
    for (int jj = 0; jj < 4; ++jj) {
      const float bv = bias[i * OC + oc + jj];
      float* orow = out + ((size_t)i * OC + oc + jj) * NP;
#pragma unroll
      for (int ni = 0; ni < 4; ++ni) {
        const int pg = p0 + ni * 16 + lcol;   // p_local = ni*16 + lcol
        orow[pg] = acc[mi][ni][jj] + bv;
      }
    }
  }
#undef STAGE
}

extern "C" void kernel_launch(void* const* d_in, const int* in_sizes, int n_in,
                              void* d_out, int out_size, void* d_ws, size_t ws_size,
                              hipStream_t stream) {
  const float* x    = (const float*)d_in[0];
  const float* w    = (const float*)d_in[1];
  const float* bias = (const float*)d_in[2];
  float* out = (float*)d_out;
  u16* wbf2 = (u16*)d_ws;   // 32*147456 u16 = 9.44 MB

  wcvt_kernel<<<dim3(32 * OC), dim3(128), 0, stream>>>(w, wbf2);
  conv_mfma<<<dim3(512), dim3(128), 0, stream>>>(x, wbf2, bias, out);
}

// Round 10
// 33.897 us; speedup vs baseline: 1.0296x; 1.0296x over previous
//
#include <hip/hip_runtime.h>

typedef unsigned short u16;
typedef unsigned int u32;
typedef __attribute__((ext_vector_type(2))) unsigned int u32x2;
typedef __attribute__((ext_vector_type(8))) short bf16x8;
typedef __attribute__((ext_vector_type(4))) float f32x4;

#define CIN 128
#define OC 128
#define NP 1024        // 32*32 spatial
#define KTOT 1152      // 9*128, k = rs*128 + c
#define NSTEP 18
#define BK 64
#define TILE_U16 8192  // 16 KB A-tile per (sample, step)
#define SAMP_U16 (NSTEP * TILE_U16)

typedef const u32 __attribute__((address_space(1)))* gptr_t;
typedef u32 __attribute__((address_space(3)))* lptr_t;

__device__ __forceinline__ u16 f2bf(float f) {
  unsigned b = __builtin_bit_cast(unsigned, f);
  b += 0x7fffu + ((b >> 16) & 1u);   // RNE; inputs are finite
  return (u16)(b >> 16);
}

// w[i][oc][c][r][s] f32 -> wbf2: per (i,step) a flat 16KB tile, PRE-SWIZZLED
// (r9-verified): tile[(row*8 + (slotk ^ (row&7)))*8 + e] = w_bf16[k=step*64+slotk*8+e]
__global__ void wcvt_kernel(const float* __restrict__ w, u16* __restrict__ wbf2) {
  __shared__ u16 lds[KTOT];
  const int blk = blockIdx.x;        // i*128 + row(oc)
  const int t = threadIdx.x;         // 0..127
  const int i = blk >> 7, row = blk & 127;
  const float* src = w + (size_t)blk * KTOT;
#pragma unroll
  for (int e = 0; e < 9; ++e) {
    int idx = t + 128 * e;           // coalesced read
    lds[idx] = f2bf(src[idx]);       // lds[c*9+rs] (input order)
  }
  __syncthreads();
  u16* dst = wbf2 + (size_t)i * SAMP_U16;
  const int rsw = row & 7;
#pragma unroll
  for (int e = 0; e < 9; ++e) {
    const int o = t + 128 * e;       // k = rs*128 + c ; rs=e, c=t
    const int s = o >> 6;            // k-step
    const int slotk = (o >> 3) & 7;
    const int ee = o & 7;
    dst[s * TILE_U16 + (row * 8 + (slotk ^ rsw)) * 8 + ee] = lds[t * 9 + e];
  }
}

// Xs: 6 rows x 34 cols x 128 ch bf16, 16B slots, XOR swizzle (r8-proven).
// Asw: TRIPLE-buffered flat 16KB A-tiles, filled by global_load_lds (linear
// dest, pre-swizzled source). LDS = 52,224 + 49,152 = 101,376 B -> 1 blk/CU.
// K-loop: counted vmcnt (never 0 until tail) + raw s_barrier; no __syncthreads.
__global__ __launch_bounds__(256, 1) void conv_mfma(
    const float* __restrict__ x,     // [32][128][32][32] f32
    const u16* __restrict__ wbf2,    // pre-swizzled A-tiles
    const float* __restrict__ bias,  // [32][1][128]
    float* __restrict__ out) {       // [32][1][128][32][32]
  __shared__ u16 Xs[6 * 34 * 128];
  __shared__ u16 Asw[3][TILE_U16];

  // grid 256 = 8 XCDs x 32; bijective XCD swizzle -> 4 samples per XCD
  const int wg = (int)blockIdx.x;
  const int swz = (wg & 7) * 32 + (wg >> 3);
  const int i  = swz >> 3;           // sample 0..31
  const int pt = swz & 7;            // pixel tile 0..7
  const int p0 = pt * 128;           // 128 px = image rows 4pt..4pt+3
  const int tid = (int)threadIdx.x;  // 256 threads, 4 waves
  const int lane = tid & 63;
  const int wid = tid >> 6;
  const int wm = wid >> 1;           // oc half
  const int wn = wid & 1;            // pixel half (2 image rows)
  const int lcol = lane & 15;
  const int lhi  = lane >> 4;        // k-subslot 0..3

  const float* xi = x + (size_t)i * CIN * NP;
  const u16*   wt = wbf2 + (size_t)i * SAMP_U16;

  // async A-stage: per wave 4 x 1KB chunks (4KB quarter per wave)
#define STAGE(step, buf) do {                                          \
    const char* _tb = (const char*)(wt + (step) * TILE_U16);           \
    _Pragma("unroll")                                                  \
    for (int _j = 0; _j < 4; ++_j) {                                   \
      const int _off = wid * 4096 + _j * 1024;                         \
      __builtin_amdgcn_global_load_lds(                                \
          (gptr_t)(_tb + _off + lane * 16),                            \
          (lptr_t)((char*)&Asw[buf][0] + _off), 16, 0, 0);             \
    }                                                                  \
  } while (0)

  STAGE(0, 0);                       // in flight during x-stage
  STAGE(1, 1);

  // ---------- one-time x-stage: rows yr = 4pt-1 .. 4pt+4 (r8-proven) ----------
  {
    const int xx = tid & 31;         // image col -> LDS col xx+1
    const int cg = tid >> 5;         // channel group 0..7 (16 ch each)
    const int col = xx + 1;
    const int csw = col & 7;
#pragma unroll
    for (int r = 0; r < 6; ++r) {
      const int yr = 4 * pt - 1 + r;
      float v[16];
      if ((unsigned)yr < 32u) {
        const float* src = xi + (size_t)(cg * 16) * NP + yr * 32 + xx;
#pragma unroll
        for (int j = 0; j < 16; ++j) v[j] = src[(size_t)j * NP];
      } else {
#pragma unroll
        for (int j = 0; j < 16; ++j) v[j] = 0.f;
      }
      u32 pk[8];
#pragma unroll
      for (int m = 0; m < 8; ++m)
        pk[m] = (u32)f2bf(v[2 * m]) | ((u32)f2bf(v[2 * m + 1]) << 16);
#pragma unroll
      for (int q = 0; q < 4; ++q) {
        const int cslot = cg * 2 + (q >> 1);
        const int idx = ((r * 34 + col) * 16 + (cslot ^ csw)) * 8 + (q & 1) * 4;
        *(u32x2*)(&Xs[idx]) = (u32x2){pk[2 * q], pk[2 * q + 1]};
      }
    }
    // column halo (col 0 and 33): zeros, 6 rows x 2 cols x 16 slots = 192
    if (tid < 192) {
      const int r = tid / 32;
      const int hc = ((tid >> 4) & 1) ? 33 : 0;
      const int s = tid & 15;
      const int idx = ((r * 34 + hc) * 16 + (s ^ (hc & 7))) * 8;
      *(bf16x8*)(&Xs[idx]) = (bf16x8){0, 0, 0, 0, 0, 0, 0, 0};
    }
  }

  f32x4 acc[4][4];
#pragma unroll
  for (int mi = 0; mi < 4; ++mi)
#pragma unroll
    for (int ni = 0; ni < 4; ++ni)
      acc[mi][ni] = (f32x4){0.f, 0.f, 0.f, 0.f};

  __syncthreads();   // prologue-only full drain: Xs + STAGE(0) + STAGE(1) ready

#pragma unroll
  for (int step = 0; step < NSTEP; ++step) {
    const int buf = step % 3;
    const int rs = step >> 1;
    const int r3 = rs / 3;
    const int dy = r3 - 1;
    const int dx = (rs - r3 * 3) - 1;
    const int c0s = (step & 1) * 8;  // channel-slot base (64ch/8)

    // keep 2 tiles in flight; issue before compute
    if (step + 2 < NSTEP) STAGE(step + 2, (step + 2) % 3);

    // ---- math: 32 MFMAs per wave per K-step ----
    __builtin_amdgcn_s_setprio(1);
#pragma unroll
    for (int kkk = 0; kkk < 2; ++kkk) {
      bf16x8 af[4], bfr[4];
#pragma unroll
      for (int mi = 0; mi < 4; ++mi) {
        const int row = wm * 64 + mi * 16 + lcol;
        const int slot = (kkk * 4 + lhi) ^ (row & 7);
        af[mi] = *(const bf16x8*)(&Asw[buf][row * BK + slot * 8]);
      }
#pragma unroll
      for (int ni = 0; ni < 4; ++ni) {
        const int srow = wn * 2 + (ni >> 1) + 1 + dy;   // in [0,5]
        const int col  = (ni & 1) * 16 + lcol + 1 + dx;
        const int cslot = c0s + kkk * 4 + lhi;
        const int idx = ((srow * 34 + col) * 16 + (cslot ^ (col & 7))) * 8;
        bfr[ni] = *(const bf16x8*)(&Xs[idx]);
      }
#pragma unroll
      for (int mi = 0; mi < 4; ++mi)
#pragma unroll
        for (int ni = 0; ni < 4; ++ni)
          acc[mi][ni] = __builtin_amdgcn_mfma_f32_16x16x32_bf16(
              af[mi], bfr[ni], acc[mi][ni], 0, 0, 0);
    }
    __builtin_amdgcn_s_setprio(0);

    // counted drain: next tile (step+1) must be resident; deeper one stays
    // in flight. vmcnt counts this wave's 4 gload_lds per STAGE.
    if (step + 2 < NSTEP) {
      asm volatile("s_waitcnt vmcnt(4)" ::: "memory");
    } else if (step + 1 < NSTEP) {
      asm volatile("s_waitcnt vmcnt(0)" ::: "memory");
    }
    if (step + 1 < NSTEP) {
      __builtin_amdgcn_s_barrier();
      __builtin_amdgcn_sched_barrier(0);
    }
  }

  // ---- epilogue (proven): C/D col=lane&15, row=(lane>>4)*4+j ----
  const int row0 = lhi * 4;
#pragma unroll
  for (int mi = 0; mi < 4; ++mi) {
    const int oc = wm * 64 + mi * 16 + row0;
#pragma unroll
    for (int jj = 0; jj < 4; ++jj) {
      const float bv = bias[i * OC + oc + jj];
      float* orow = out + ((size_t)i * OC + oc + jj) * NP;
#pragma unroll
      for (int ni = 0; ni < 4; ++ni) {
        const int pg = p0 + wn * 64 + ni * 16 + lcol;
        orow[pg] = acc[mi][ni][jj] + bv;
      }
    }
  }
#undef STAGE
}

extern "C" void kernel_launch(void* const* d_in, const int* in_sizes, int n_in,
                              void* d_out, int out_size, void* d_ws, size_t ws_size,
                              hipStream_t stream) {
  const float* x    = (const float*)d_in[0];
  const float* w    = (const float*)d_in[1];
  const float* bias = (const float*)d_in[2];
  float* out = (float*)d_out;
  u16* wbf2 = (u16*)d_ws;   // 32*147456 u16 = 9.44 MB

  wcvt_kernel<<<dim3(32 * OC), dim3(128), 0, stream>>>(w, wbf2);
  conv_mfma<<<dim3(256), dim3(256), 0, stream>>>(x, wbf2, bias, out);
}

// Round 11
// 30.642 us; speedup vs baseline: 1.1389x; 1.1062x over previous
//
#include <hip/hip_runtime.h>

typedef unsigned short u16;
typedef unsigned int u32;
typedef __attribute__((ext_vector_type(2))) unsigned int u32x2;
typedef __attribute__((ext_vector_type(8))) short bf16x8;
typedef __attribute__((ext_vector_type(4))) float f32x4;

#define CIN 128
#define OC 128
#define NP 1024        // 32*32 spatial
#define KTOT 1152      // 9*128, k = rs*128 + c
#define NSTEP 18
#define BK 64
#define TILE_U16 8192  // 16 KB A-tile per (sample, step)
#define SAMP_U16 (NSTEP * TILE_U16)

typedef const u32 __attribute__((address_space(1)))* gptr_t;
typedef u32 __attribute__((address_space(3)))* lptr_t;

__device__ __forceinline__ u16 f2bf(float f) {
  unsigned b = __builtin_bit_cast(unsigned, f);
  b += 0x7fffu + ((b >> 16) & 1u);   // RNE; inputs are finite
  return (u16)(b >> 16);
}

// w[i][oc][c][r][s] f32 -> wbf2: per (i,step) a flat 16KB tile, PRE-SWIZZLED
// (r9-verified): tile[(row*8 + (slotk ^ (row&7)))*8 + e] = w_bf16[k=step*64+slotk*8+e]
__global__ void wcvt_kernel(const float* __restrict__ w, u16* __restrict__ wbf2) {
  __shared__ u16 lds[KTOT];
  const int blk = blockIdx.x;        // i*128 + row(oc)
  const int t = threadIdx.x;         // 0..127
  const int i = blk >> 7, row = blk & 127;
  const float* src = w + (size_t)blk * KTOT;
#pragma unroll
  for (int e = 0; e < 9; ++e) {
    int idx = t + 128 * e;           // coalesced read
    lds[idx] = f2bf(src[idx]);       // lds[c*9+rs] (input order)
  }
  __syncthreads();
  u16* dst = wbf2 + (size_t)i * SAMP_U16;
  const int rsw = row & 7;
#pragma unroll
  for (int e = 0; e < 9; ++e) {
    const int o = t + 128 * e;       // k = rs*128 + c ; rs=e, c=t
    const int s = o >> 6;            // k-step
    const int slotk = (o >> 3) & 7;
    const int ee = o & 7;
    dst[s * TILE_U16 + (row * 8 + (slotk ^ rsw)) * 8 + ee] = lds[t * 9 + e];
  }
}

// Xs: 6 rows x 34 cols x 128 ch bf16, 16B slots, XOR swizzle (r8/r10-proven).
// Asw: 4 x 16KB A-step-buffers (steps s..s+3 resident), filled by
// global_load_lds from pre-swizzled tiles. LDS = 52,224 + 65,536 = 117,760 B.
// Schedule: per K-step phase {stage(s+2); vmcnt(4); s_barrier; ds_read x12;
// setprio(1); MFMA x16; setprio(0); s_barrier}. vmcnt derived by FIFO ledger.
__global__ __launch_bounds__(512, 1) void conv_mfma(
    const float* __restrict__ x,     // [32][128][32][32] f32
    const u16* __restrict__ wbf2,    // pre-swizzled A-tiles
    const float* __restrict__ bias,  // [32][1][128]
    float* __restrict__ out) {       // [32][1][128][32][32]
  __shared__ u16 Xs[6 * 34 * 128];
  __shared__ u16 Asw[4][TILE_U16];

  // grid 256 = 8 XCDs x 32; bijective XCD swizzle -> 4 samples per XCD
  const int wg = (int)blockIdx.x;
  const int swz = (wg & 7) * 32 + (wg >> 3);
  const int i  = swz >> 3;           // sample 0..31
  const int pt = swz & 7;            // pixel tile 0..7
  const int p0 = pt * 128;           // 128 px = image rows 4pt..4pt+3
  const int tid = (int)threadIdx.x;  // 512 threads, 8 waves
  const int lane = tid & 63;
  const int wid = tid >> 6;          // 0..7
  const int wm = wid >> 2;           // oc half (64 oc)
  const int wn = wid & 3;            // image row within tile (32 px)
  const int lcol = lane & 15;
  const int lhi  = lane >> 4;        // k-subslot 0..3

  const float* xi = x + (size_t)i * CIN * NP;
  const u16*   wt = wbf2 + (size_t)i * SAMP_U16;

  // async A-stage: 2 chunks of 1KB per wave (16KB = 8 waves x 2KB)
#define STAGE(step) do {                                               \
    const char* _tb = (const char*)(wt + (step) * TILE_U16);           \
    char* _lb = (char*)&Asw[(step) & 3][0];                            \
    _Pragma("unroll")                                                  \
    for (int _j = 0; _j < 2; ++_j) {                                   \
      const int _off = wid * 2048 + _j * 1024;                         \
      __builtin_amdgcn_global_load_lds(                                \
          (gptr_t)(_tb + _off + lane * 16),                            \
          (lptr_t)(_lb + _off), 16, 0, 0);                             \
    }                                                                  \
  } while (0)

  STAGE(0);                          // queue: [0,0,1,1] in flight
  STAGE(1);

  // ---------- one-time x-stage: rows yr = 4pt-1 .. 4pt+4 (proven) ----------
  {
    const int xx = tid & 31;         // image col -> LDS col xx+1
    const int cg = (tid >> 5) & 7;   // 16-ch group
    const int rh = tid >> 8;         // row-half: rows 0-2 or 3-5
    const int col = xx + 1;
    const int csw = col & 7;
#pragma unroll
    for (int rr = 0; rr < 3; ++rr) {
      const int r = rh * 3 + rr;
      const int yr = 4 * pt - 1 + r;
      float v[16];
      if ((unsigned)yr < 32u) {
        const float* src = xi + (size_t)(cg * 16) * NP + yr * 32 + xx;
#pragma unroll
        for (int j = 0; j < 16; ++j) v[j] = src[(size_t)j * NP];
      } else {
#pragma unroll
        for (int j = 0; j < 16; ++j) v[j] = 0.f;
      }
      u32 pk[8];
#pragma unroll
      for (int m = 0; m < 8; ++m)
        pk[m] = (u32)f2bf(v[2 * m]) | ((u32)f2bf(v[2 * m + 1]) << 16);
#pragma unroll
      for (int q = 0; q < 4; ++q) {
        const int cslot = cg * 2 + (q >> 1);
        const int idx = ((r * 34 + col) * 16 + (cslot ^ csw)) * 8 + (q & 1) * 4;
        *(u32x2*)(&Xs[idx]) = (u32x2){pk[2 * q], pk[2 * q + 1]};
      }
    }
    // column halo (col 0 and 33): zeros, 6 rows x 2 cols x 16 slots = 192
    if (tid < 192) {
      const int r = tid / 32;
      const int hc = ((tid >> 4) & 1) ? 33 : 0;
      const int s = tid & 15;
      const int idx = ((r * 34 + hc) * 16 + (s ^ (hc & 7))) * 8;
      *(bf16x8*)(&Xs[idx]) = (bf16x8){0, 0, 0, 0, 0, 0, 0, 0};
    }
  }

  f32x4 acc[4][2];
#pragma unroll
  for (int mi = 0; mi < 4; ++mi)
#pragma unroll
    for (int ni = 0; ni < 2; ++ni)
      acc[mi][ni] = (f32x4){0.f, 0.f, 0.f, 0.f};

  __syncthreads();                   // Xs visible to all waves

#pragma unroll
  for (int step = 0; step < NSTEP; ++step) {
    const int buf = step & 3;
    const int rs = step >> 1;
    const int r3 = rs / 3;
    const int dy = r3 - 1;
    const int dx = (rs - r3 * 3) - 1;
    const int c0s = (step & 1) * 8;  // channel-slot base

    // stage step+2 into buf (step+2)&3 (its last reader was step-2: done)
    if (step + 2 < NSTEP) STAGE(step + 2);

    // FIFO ledger: worst-case in flight = {s,s, s+1,s+1, s+2,s+2}.
    // Need step s resident -> vmcnt(4); tail: s=16 ->2, s=17 ->0.
    if (step + 2 < NSTEP) {
      asm volatile("s_waitcnt vmcnt(4)" ::: "memory");
    } else if (step + 1 < NSTEP) {
      asm volatile("s_waitcnt vmcnt(2)" ::: "memory");
    } else {
      asm volatile("s_waitcnt vmcnt(0)" ::: "memory");
    }
    __builtin_amdgcn_s_barrier();    // buf(step) ready for ALL waves
    __builtin_amdgcn_sched_barrier(0);

    // ---- 12 ds_read + 16 MFMA cluster ----
    bf16x8 af[2][4], bfr[2][2];
#pragma unroll
    for (int kkk = 0; kkk < 2; ++kkk) {
#pragma unroll
      for (int mi = 0; mi < 4; ++mi) {
        const int row = wm * 64 + mi * 16 + lcol;
        const int slot = (kkk * 4 + lhi) ^ (row & 7);
        af[kkk][mi] = *(const bf16x8*)(&Asw[buf][row * BK + slot * 8]);
      }
#pragma unroll
      for (int ni = 0; ni < 2; ++ni) {
        const int srow = wn + 1 + dy;                 // in [0,5]
        const int col  = ni * 16 + lcol + 1 + dx;     // in [0,33]
        const int cslot = c0s + kkk * 4 + lhi;
        const int idx = ((srow * 34 + col) * 16 + (cslot ^ (col & 7))) * 8;
        bfr[kkk][ni] = *(const bf16x8*)(&Xs[idx]);
      }
    }
    __builtin_amdgcn_s_setprio(1);
#pragma unroll
    for (int kkk = 0; kkk < 2; ++kkk)
#pragma unroll
      for (int mi = 0; mi < 4; ++mi)
#pragma unroll
        for (int ni = 0; ni < 2; ++ni)
          acc[mi][ni] = __builtin_amdgcn_mfma_f32_16x16x32_bf16(
              af[kkk][mi], bfr[kkk][ni], acc[mi][ni], 0, 0, 0);
    __builtin_amdgcn_s_setprio(0);
    __builtin_amdgcn_s_barrier();    // phase gate: keep waves in lockstep
  }

  // ---- epilogue (proven): C/D col=lane&15, row=(lane>>4)*4+j ----
  const int row0 = lhi * 4;
#pragma unroll
  for (int mi = 0; mi < 4; ++mi) {
    const int oc = wm * 64 + mi * 16 + row0;
#pragma unroll
    for (int jj = 0; jj < 4; ++jj) {
      const float bv = bias[i * OC + oc + jj];
      float* orow = out + ((size_t)i * OC + oc + jj) * NP;
#pragma unroll
      for (int ni = 0; ni < 2; ++ni) {
        const int pg = p0 + wn * 32 + ni * 16 + lcol;
        orow[pg] = acc[mi][ni][jj] + bv;
      }
    }
  }
#undef STAGE
}

extern "C" void kernel_launch(void* const* d_in, const int* in_sizes, int n_in,
                              void* d_out, int out_size, void* d_ws, size_t ws_size,
                              hipStream_t stream) {
  const float* x    = (const float*)d_in[0];
  const float* w    = (const float*)d_in[1];
  const float* bias = (const float*)d_in[2];
  float* out = (float*)d_out;
  u16* wbf2 = (u16*)d_ws;   // 32*147456 u16 = 9.44 MB

  wcvt_kernel<<<dim3(32 * OC), dim3(128), 0, stream>>>(w, wbf2);
  conv_mfma<<<dim3(256), dim3(512), 0, stream>>>(x, wbf2, bias, out);
}